// Round 1
// baseline (1968.535 us; speedup 1.0000x reference)
//
#include <hip/hip_runtime.h>

#define WINDOW 128
#define STRIDE 16
#define NWIN   249     // (4096-128)/16 + 1
#define NF     128
#define SEQ    4096

typedef _Float16 f16x8 __attribute__((ext_vector_type(8)));
typedef float    f32x4 __attribute__((ext_vector_type(4)));

// One block computes one (b, w) 128x128 Gram tile: C = W^T W / 128,
// W = input[b, w*16 : w*16+128, :]  (128 window rows x 128 features).
// 256 threads = 4 waves; 64 MFMA 16x16 tiles, 16 per wave (2 tile-rows x 8 tile-cols).
__global__ __launch_bounds__(256) void pcc_kernel(const float* __restrict__ in,
                                                  float* __restrict__ out) {
    // LDS: W transposed, Wt[f][l] as f16, 16B-chunk XOR swizzle on l-chunks.
    // phys(f, l) = f*128 + (((l>>3) ^ (f&15))<<3) + (l&7)
    __shared__ _Float16 lds[NF * WINDOW];   // 32 KB

    const int tid = threadIdx.x;
    const int w = blockIdx.x;
    const int b = blockIdx.y;

    const float* src = in + ((size_t)b * SEQ + (size_t)w * STRIDE) * NF;

    // ---- stage: read rows l (coalesced over f), convert f16, store transposed ----
    {
        const int f  = tid & 127;     // feature handled by this thread
        const int lg = tid >> 7;      // 0..1
        const int fx = f & 15;
        #pragma unroll
        for (int pass = 0; pass < 8; ++pass) {
            const int l0 = pass * 16 + lg * 8;
            f16x8 v;
            #pragma unroll
            for (int j = 0; j < 8; ++j) {
                v[j] = (_Float16)src[(size_t)(l0 + j) * NF + f];
            }
            const int chunk = (l0 >> 3) ^ fx;
            *(f16x8*)&lds[f * WINDOW + (chunk << 3)] = v;   // ds_write_b128
        }
    }
    __syncthreads();

    const int lane = tid & 63;
    const int wid  = tid >> 6;    // 0..3
    const int q    = lane >> 4;   // quad 0..3
    const int c    = lane & 15;

    f32x4 acc[2][8];
    #pragma unroll
    for (int i = 0; i < 2; ++i)
        #pragma unroll
        for (int t = 0; t < 8; ++t)
            acc[i][t] = f32x4{0.f, 0.f, 0.f, 0.f};

    // K-loop over l in steps of 32. frag[t][j] = W[32ks + 8q + j][16t + c],
    // which is simultaneously the A-operand for tile-row t and the B-operand
    // for tile-col t (A[m=c][k=8q+j], B[k=8q+j][n=c] have mirrored layouts).
    #pragma unroll
    for (int ks = 0; ks < 4; ++ks) {
        f16x8 frag[8];
        #pragma unroll
        for (int t = 0; t < 8; ++t) {
            const int f = 16 * t + c;
            const int chunk = (4 * ks + q) ^ c;           // f&15 == c here
            frag[t] = *(const f16x8*)&lds[f * WINDOW + (chunk << 3)];  // ds_read_b128
        }
        #pragma unroll
        for (int i = 0; i < 2; ++i) {
            const int ti = 2 * wid + i;
            #pragma unroll
            for (int t = 0; t < 8; ++t)
                acc[i][t] = __builtin_amdgcn_mfma_f32_16x16x32_f16(
                    frag[ti], frag[t], acc[i][t], 0, 0, 0);
        }
    }

    // ---- epilogue: C/D layout col=lane&15, row=quad*4+reg (m89-verified) ----
    float* dst = out + (size_t)(b * NWIN + w) * (NF * NF);
    const float scale = 1.0f / (float)WINDOW;
    #pragma unroll
    for (int i = 0; i < 2; ++i) {
        const int ti = 2 * wid + i;
        #pragma unroll
        for (int t = 0; t < 8; ++t) {
            #pragma unroll
            for (int r = 0; r < 4; ++r) {
                const int row = 16 * ti + 4 * q + r;
                const int col = 16 * t + c;
                dst[row * NF + col] = acc[i][t][r] * scale;
            }
        }
    }
}

extern "C" void kernel_launch(void* const* d_in, const int* in_sizes, int n_in,
                              void* d_out, int out_size, void* d_ws, size_t ws_size,
                              hipStream_t stream) {
    (void)in_sizes; (void)n_in; (void)d_ws; (void)ws_size; (void)out_size;
    const float* in = (const float*)d_in[0];
    float* out = (float*)d_out;
    dim3 grid(NWIN, 16);
    pcc_kernel<<<grid, dim3(256, 1, 1), 0, stream>>>(in, out);
}

// Round 2
// 317.851 us; speedup vs baseline: 6.1933x; 6.1933x over previous
//
#include <hip/hip_runtime.h>

#define WINDOW 128
#define STRIDE 16
#define NWIN   249     // (4096-128)/16 + 1
#define NF     128
#define SEQ    4096

typedef _Float16 f16x8 __attribute__((ext_vector_type(8)));
typedef float    f32x4 __attribute__((ext_vector_type(4)));

// One block computes one (b, w) 128x128 Gram tile: C = W^T W / 128,
// W = input[b, w*16 : w*16+128, :]  (128 window rows l x 128 features f).
// 256 threads = 4 waves; 64 MFMA 16x16 tiles, 16 per wave (2 tile-rows x 8 tile-cols).
// NOTE: no runtime-indexed register arrays anywhere (R1 lesson: frag[ti] with
// runtime ti forced the whole operand array to scratch -> 15x slowdown).
__global__ __launch_bounds__(256) void pcc_kernel(const float* __restrict__ in,
                                                  float* __restrict__ out) {
    // LDS: W transposed, Wt[f][l] as f16, 16B-chunk XOR swizzle on l-chunks.
    // phys(f, l) = f*128 + (((l>>3) ^ (f&15))<<3) + (l&7)
    __shared__ _Float16 lds[NF * WINDOW];   // 32 KB

    const int tid = threadIdx.x;
    const int w = blockIdx.x;
    const int b = blockIdx.y;

    const float* src = in + ((size_t)b * SEQ + (size_t)w * STRIDE) * NF;

    // ---- stage: global_load_dwordx4 (row-contiguous), cvt f16, ds_write_b128 transposed ----
    // thread covers a 8(l) x 4(f) sub-block per pass; 2 passes.
    {
        const int f0 = 4 * (tid & 31);          // feature group
        const int lb = 8 * (tid >> 5);          // l-block within pass half
        #pragma unroll
        for (int pass = 0; pass < 2; ++pass) {
            const int l0 = pass * 64 + lb;
            f32x4 rows[8];
            #pragma unroll
            for (int j = 0; j < 8; ++j)
                rows[j] = *(const f32x4*)&src[(size_t)(l0 + j) * NF + f0];
            #pragma unroll
            for (int d = 0; d < 4; ++d) {
                const int f = f0 + d;
                f16x8 v;
                #pragma unroll
                for (int j = 0; j < 8; ++j)
                    v[j] = (_Float16)rows[j][d];
                const int chunk = (l0 >> 3) ^ (f & 15);
                *(f16x8*)&lds[f * WINDOW + (chunk << 3)] = v;   // ds_write_b128
            }
        }
    }
    __syncthreads();

    const int lane = tid & 63;
    const int wid  = tid >> 6;    // 0..3
    const int q    = lane >> 4;   // quad 0..3
    const int c    = lane & 15;

    f32x4 acc[2][8];
    #pragma unroll
    for (int i = 0; i < 2; ++i)
        #pragma unroll
        for (int t = 0; t < 8; ++t)
            acc[i][t] = f32x4{0.f, 0.f, 0.f, 0.f};

    // K-loop over l in steps of 32. fragment(f)[j] = W[32ks + 8q + j][f];
    // the same fragment serves as A for tile-row f/16 and B for tile-col f/16.
    #pragma unroll
    for (int ks = 0; ks < 4; ++ks) {
        const int chunk = ((4 * ks + q) ^ c) << 3;   // (f&15)==c for all frags below
        // B operands: all 8 tile-cols
        f16x8 bfrag[8];
        #pragma unroll
        for (int t = 0; t < 8; ++t)
            bfrag[t] = *(const f16x8*)&lds[(16 * t + c) * WINDOW + chunk];
        // A operands: this wave's 2 tile-rows (explicit loads, compile-time reg indices)
        f16x8 afrag0 = *(const f16x8*)&lds[(16 * (2 * wid + 0) + c) * WINDOW + chunk];
        f16x8 afrag1 = *(const f16x8*)&lds[(16 * (2 * wid + 1) + c) * WINDOW + chunk];
        #pragma unroll
        for (int t = 0; t < 8; ++t) {
            acc[0][t] = __builtin_amdgcn_mfma_f32_16x16x32_f16(afrag0, bfrag[t], acc[0][t], 0, 0, 0);
            acc[1][t] = __builtin_amdgcn_mfma_f32_16x16x32_f16(afrag1, bfrag[t], acc[1][t], 0, 0, 0);
        }
    }

    // ---- epilogue: C/D layout col=lane&15, row=quad*4+reg (m89-verified) ----
    float* dst = out + (size_t)(b * NWIN + w) * (NF * NF);
    const float scale = 1.0f / (float)WINDOW;
    #pragma unroll
    for (int i = 0; i < 2; ++i) {
        const int rowbase = 16 * (2 * wid + i) + 4 * q;
        #pragma unroll
        for (int t = 0; t < 8; ++t) {
            #pragma unroll
            for (int r = 0; r < 4; ++r) {
                const int row = rowbase + r;
                const int col = 16 * t + c;
                dst[row * NF + col] = acc[i][t][r] * scale;
            }
        }
    }
}

extern "C" void kernel_launch(void* const* d_in, const int* in_sizes, int n_in,
                              void* d_out, int out_size, void* d_ws, size_t ws_size,
                              hipStream_t stream) {
    (void)in_sizes; (void)n_in; (void)d_ws; (void)ws_size; (void)out_size;
    const float* in = (const float*)d_in[0];
    float* out = (float*)d_out;
    dim3 grid(NWIN, 16);
    pcc_kernel<<<grid, dim3(256, 1, 1), 0, stream>>>(in, out);
}

// Round 3
// 295.580 us; speedup vs baseline: 6.6599x; 1.0753x over previous
//
#include <hip/hip_runtime.h>

#define WINDOW 128
#define STRIDE 16
#define NWIN   249     // (4096-128)/16 + 1
#define NF     128
#define SEQ    4096
#define LROWS  160     // LDS l-capacity: 20 chunks of 8 rows (144 used)

typedef _Float16 f16;
typedef _Float16 f16x2 __attribute__((ext_vector_type(2)));
typedef _Float16 f16x8 __attribute__((ext_vector_type(8)));
typedef float    f32x4 __attribute__((ext_vector_type(4)));

union V8 { f16x8 v8; f16x2 v2[4]; };

// Stage 8 rows x 4 features: f32 global -> (x 1/sqrt(128), f16) -> LDS transposed.
// LDS layout: lds[f * LROWS + chunk*8 + (l&7)], chunk swizzled:
//   l < 128 : chunk = (l>>3) ^ (f&15)          (chunks 0..15)
//   l >= 128: chunk = 16 + (((l>>3)&3) ^ (f&3)) (chunks 16..19)
__device__ __forceinline__ void stage8(const float* __restrict__ src, f16* lds,
                                       int f0, int l0) {
    f32x4 rows[8];
    #pragma unroll
    for (int j = 0; j < 8; ++j)
        rows[j] = *(const f32x4*)&src[(size_t)(l0 + j) * NF + f0];
    const int cbase = l0 >> 3;
    #pragma unroll
    for (int d = 0; d < 4; ++d) {
        const int f = f0 + d;
        V8 u;
        #pragma unroll
        for (int jj = 0; jj < 4; ++jj) {
            auto p = __builtin_amdgcn_cvt_pkrtz(rows[2 * jj][d], rows[2 * jj + 1][d]);
            u.v2[jj] = *(f16x2*)&p;
        }
        // fold the 1/WINDOW PCC scale in as 1/sqrt(128) on each operand (v_pk_mul_f16)
        u.v8 = u.v8 * (f16)0.08838834764831845f;
        const int ch = (l0 < 128) ? (cbase ^ (f & 15))
                                  : (16 + ((cbase & 3) ^ (f & 3)));
        *(f16x8*)&lds[f * LROWS + ch * 8] = u.v8;   // ds_write_b128
    }
}

// Compute one 128x128 Gram tile from staged rows [8*CO .. 8*CO+127] and store.
// CO = chunk offset (0 for window A, 2 for window B, +16 rows).
// fragment(f)[j] = Wscaled[l = 8*CO + 32ks + 8q + j][f]; serves as both the
// A operand of tile-row f/16 and the B operand of tile-col f/16.
template<int CO>
__device__ __forceinline__ void compute_and_store(const f16* lds, int c, int q,
                                                  int wid, float* __restrict__ dst) {
    f32x4 acc[2][8];
    #pragma unroll
    for (int i = 0; i < 2; ++i)
        #pragma unroll
        for (int t = 0; t < 8; ++t)
            acc[i][t] = f32x4{0.f, 0.f, 0.f, 0.f};

    #pragma unroll
    for (int ks = 0; ks < 4; ++ks) {
        const int clog = CO + 4 * ks + q;
        int pc;
        if (CO == 0) pc = clog ^ c;                       // always main region
        else pc = (clog < 16) ? (clog ^ c) : (16 + ((clog & 3) ^ (c & 3)));
        const int off = pc * 8;                           // same for all frags (f&15==c)

        f16x8 bfrag[8];
        #pragma unroll
        for (int t = 0; t < 8; ++t)
            bfrag[t] = *(const f16x8*)&lds[(16 * t + c) * LROWS + off];
        const f16x8 a0 = *(const f16x8*)&lds[(16 * (2 * wid + 0) + c) * LROWS + off];
        const f16x8 a1 = *(const f16x8*)&lds[(16 * (2 * wid + 1) + c) * LROWS + off];
        #pragma unroll
        for (int t = 0; t < 8; ++t) {
            acc[0][t] = __builtin_amdgcn_mfma_f32_16x16x32_f16(a0, bfrag[t], acc[0][t], 0, 0, 0);
            acc[1][t] = __builtin_amdgcn_mfma_f32_16x16x32_f16(a1, bfrag[t], acc[1][t], 0, 0, 0);
        }
    }

    // C/D layout: col = lane&15, row = 4*quad + reg (m89-verified); scale pre-folded.
    #pragma unroll
    for (int i = 0; i < 2; ++i) {
        const int rowbase = 16 * (2 * wid + i) + 4 * q;
        #pragma unroll
        for (int t = 0; t < 8; ++t)
            #pragma unroll
            for (int r = 0; r < 4; ++r)
                dst[(rowbase + r) * NF + 16 * t + c] = acc[i][t][r];
    }
}

// One block: stage 144 rows (f16, transposed, swizzled) and compute TWO
// consecutive windows (share 112 of 128 rows). 256 threads = 4 waves.
__global__ __launch_bounds__(256) void pcc_kernel(const float* __restrict__ in,
                                                  float* __restrict__ out) {
    __shared__ f16 lds[NF * LROWS];   // 40 KB -> 4 blocks/CU

    const int tid = threadIdx.x;
    const int wp  = blockIdx.x;       // window pair 0..124
    const int b   = blockIdx.y;
    const bool full = (wp < 124);     // wp==124 handles only window 248
    const int stage_base = full ? 32 * wp : (SEQ - 144);   // 3952

    const float* src = in + ((size_t)b * SEQ + stage_base) * NF;
    const int f0 = 4 * (tid & 31);
    const int lh = tid >> 5;

    stage8(src, lds, f0, 8 * lh);            // rows 0..63
    stage8(src, lds, f0, 64 + 8 * lh);       // rows 64..127
    if (tid < 64)                            // wave 0 only: rows 128..143
        stage8(src, lds, f0, 128 + 8 * lh);
    __syncthreads();

    const int lane = tid & 63;
    const int wid  = tid >> 6;
    const int q    = lane >> 4;
    const int c    = lane & 15;

    float* outb = out + (size_t)b * NWIN * (NF * NF);
    if (full)
        compute_and_store<0>(lds, c, q, wid, outb + (size_t)(2 * wp) * (NF * NF));
    const int w1 = full ? (2 * wp + 1) : (NWIN - 1);
    compute_and_store<2>(lds, c, q, wid, outb + (size_t)w1 * (NF * NF));
}

extern "C" void kernel_launch(void* const* d_in, const int* in_sizes, int n_in,
                              void* d_out, int out_size, void* d_ws, size_t ws_size,
                              hipStream_t stream) {
    (void)in_sizes; (void)n_in; (void)d_ws; (void)ws_size; (void)out_size;
    const float* in = (const float*)d_in[0];
    float* out = (float*)d_out;
    dim3 grid(125, 16);
    pcc_kernel<<<grid, dim3(256, 1, 1), 0, stream>>>(in, out);
}